// Round 1
// baseline (29906.601 us; speedup 1.0000x reference)
//
#include <hip/hip_runtime.h>

#define BB 256
#define SS 64
#define HH 512
#define VV 32000

__device__ __forceinline__ float sigm(float x) { return 1.0f / (1.0f + __expf(-x)); }
__device__ __forceinline__ float tanh_fast(float x) { return 1.0f - 2.0f / (__expf(2.0f * x) + 1.0f); }

// ---------------------------------------------------------------------------
// fb_step: one time step of the forward AND backward LSTM cells (H=512).
// grid = 256 blocks: blocks [0,128) = forward cell, [128,256) = backward cell.
// Each block: all 256 batches x 4 hidden units (all 4 gates), K = 512(emb)+512(h).
// Thread t: batches {t&127, (t&127)+128}, unit-pair (t>>7)*2 + {0,1}.
// ---------------------------------------------------------------------------
__global__ __launch_bounds__(256)
void fb_step_k(const int* __restrict__ x, const float* __restrict__ W_emb,
               const float* __restrict__ Wih_f, const float* __restrict__ Whh_f,
               const float* __restrict__ bih_f, const float* __restrict__ bhh_f,
               const float* __restrict__ Wih_b, const float* __restrict__ Whh_b,
               const float* __restrict__ bih_b, const float* __restrict__ bhh_b,
               const float* __restrict__ hf_r, float* __restrict__ hf_w, float* __restrict__ cf,
               const float* __restrict__ hb_r, float* __restrict__ hb_w, float* __restrict__ cb,
               int t)
{
    constexpr int U = 4;
    constexpr int NT = HH / U;           // 128 unit-tiles per cell
    const int bi_ = blockIdx.x;
    const int cell = bi_ / NT;           // 0 = forward, 1 = backward
    const int u0 = (bi_ % NT) * U;
    const int tid = threadIdx.x;
    const int b_lo = tid & 127;
    const int up = tid >> 7;             // unit-pair select

    const float* Wih = cell ? Wih_b : Wih_f;
    const float* Whh = cell ? Whh_b : Whh_f;
    const float* bih = cell ? bih_b : bih_f;
    const float* bhh = cell ? bhh_b : bhh_f;
    const float* h_r = cell ? hb_r : hf_r;
    float* h_w = cell ? hb_w : hf_w;
    float* c   = cell ? cb   : cf;
    // seq = emb.reshape(S,B,H) is a raw view: token(step s2, batch b) = x_flat[s2*B + b]
    const int s2 = cell ? (SS - 1 - t) : t;

    __shared__ int   toks[BB];
    __shared__ float actv[BB * 37];      // act chunk [b][k], stride 37 (bank-safe)
    __shared__ float4 wv[16][9];         // weights [ulocal*4+gate][k/4], pad

    toks[tid] = x[s2 * BB + tid];

    float acc[2][2][4];                  // [batch-half][unit][gate i,f,g,o]
#pragma unroll
    for (int uii = 0; uii < 2; ++uii)
#pragma unroll
        for (int g = 0; g < 4; ++g) {
            int u = u0 + up * 2 + uii;
            float bs = bih[g * HH + u] + bhh[g * HH + u];
            acc[0][uii][g] = bs;
            acc[1][uii][g] = bs;
        }

    for (int ph = 0; ph < 2; ++ph) {     // ph 0: embedding input, ph 1: hidden
        const float* Wmat = ph ? Whh : Wih;
        for (int kc = 0; kc < HH; kc += 32) {
            __syncthreads();
            // stage activations: 256 rows x 32 k
#pragma unroll
            for (int i = 0; i < 8; ++i) {
                int flat = i * BB + tid;
                int row = flat >> 3;
                int kk = flat & 7;
                float4 v;
                if (ph == 0) {
                    int tok = toks[row];
                    v = (tok == 0) ? make_float4(0.f, 0.f, 0.f, 0.f)
                                   : *(const float4*)&W_emb[(size_t)tok * HH + kc + kk * 4];
                } else {
                    v = *(const float4*)&h_r[(size_t)row * HH + kc + kk * 4];
                }
                float* dst = &actv[row * 37 + kk * 4];
                dst[0] = v.x; dst[1] = v.y; dst[2] = v.z; dst[3] = v.w;
            }
            // stage weights: 16 gate-rows x 32 k
            if (tid < 128) {
                int row = tid >> 3;      // ulocal*4+gate
                int kk = tid & 7;
                int ul = row >> 2, g = row & 3;
                wv[row][kk] = *(const float4*)&Wmat[(size_t)(g * HH + u0 + ul) * HH + kc + kk * 4];
            }
            __syncthreads();
#pragma unroll
            for (int kk = 0; kk < 8; ++kk) {
                float a0[2][4];
#pragma unroll
                for (int bb = 0; bb < 2; ++bb) {
                    const float* ap = &actv[(b_lo + bb * 128) * 37 + kk * 4];
                    a0[bb][0] = ap[0]; a0[bb][1] = ap[1]; a0[bb][2] = ap[2]; a0[bb][3] = ap[3];
                }
#pragma unroll
                for (int uii = 0; uii < 2; ++uii)
#pragma unroll
                    for (int g = 0; g < 4; ++g) {
                        float4 w = wv[(up * 2 + uii) * 4 + g][kk];
#pragma unroll
                        for (int bb = 0; bb < 2; ++bb)
                            acc[bb][uii][g] += a0[bb][0] * w.x + a0[bb][1] * w.y
                                             + a0[bb][2] * w.z + a0[bb][3] * w.w;
                    }
            }
        }
    }

    // pointwise LSTM + store (gate order i,f,g,o)
#pragma unroll
    for (int bb = 0; bb < 2; ++bb) {
        int b = b_lo + bb * 128;
        int u = u0 + up * 2;
        float2 cold = *(const float2*)&c[(size_t)b * HH + u];
        float2 cnew, hnew;
#pragma unroll
        for (int uii = 0; uii < 2; ++uii) {
            float i_ = sigm(acc[bb][uii][0]);
            float f_ = sigm(acc[bb][uii][1]);
            float g_ = tanh_fast(acc[bb][uii][2]);
            float o_ = sigm(acc[bb][uii][3]);
            float co = uii ? cold.y : cold.x;
            float c2 = f_ * co + i_ * g_;
            float h2 = o_ * tanh_fast(c2);
            if (uii == 0) { cnew.x = c2; hnew.x = h2; } else { cnew.y = c2; hnew.y = h2; }
        }
        *(float2*)&c[(size_t)b * HH + u] = cnew;
        *(float2*)&h_w[(size_t)b * HH + u] = hnew;
    }
}

// ---------------------------------------------------------------------------
// comb_step: one time step of the combiner cell (hidden 2H=1024).
// grid = 256 blocks x 4 units. K = 512(hf) + 512(hb) + 1024(hc).
// ---------------------------------------------------------------------------
__global__ __launch_bounds__(256)
void comb_step_k(const float* __restrict__ hfin, const float* __restrict__ hbin,
                 const float* __restrict__ Wih_c, const float* __restrict__ Whh_c,
                 const float* __restrict__ bih_c, const float* __restrict__ bhh_c,
                 const float* __restrict__ hc_r, float* __restrict__ hc_w,
                 float* __restrict__ cc)
{
    constexpr int NU = 2 * HH;           // 1024 units, also in-feature count
    const int u0 = blockIdx.x * 4;
    const int tid = threadIdx.x;
    const int b_lo = tid & 127;
    const int up = tid >> 7;

    __shared__ float actv[BB * 37];
    __shared__ float4 wv[16][9];

    float acc[2][2][4];
#pragma unroll
    for (int uii = 0; uii < 2; ++uii)
#pragma unroll
        for (int g = 0; g < 4; ++g) {
            int u = u0 + up * 2 + uii;
            float bs = bih_c[g * NU + u] + bhh_c[g * NU + u];
            acc[0][uii][g] = bs;
            acc[1][uii][g] = bs;
        }

    for (int kc = 0; kc < 2048; kc += 32) {
        __syncthreads();
#pragma unroll
        for (int i = 0; i < 8; ++i) {
            int flat = i * BB + tid;
            int row = flat >> 3;
            int kk = flat & 7;
            const float* src;
            size_t off;
            if (kc < 512)       { src = hfin; off = (size_t)row * HH + kc + kk * 4; }
            else if (kc < 1024) { src = hbin; off = (size_t)row * HH + (kc - 512) + kk * 4; }
            else                { src = hc_r; off = (size_t)row * NU + (kc - 1024) + kk * 4; }
            float4 v = *(const float4*)&src[off];
            float* dst = &actv[row * 37 + kk * 4];
            dst[0] = v.x; dst[1] = v.y; dst[2] = v.z; dst[3] = v.w;
        }
        if (tid < 128) {
            int row = tid >> 3;
            int kk = tid & 7;
            int ul = row >> 2, g = row & 3;
            const float* Wmat = (kc < 1024) ? Wih_c : Whh_c;
            int kloc = (kc < 1024) ? kc : (kc - 1024);
            wv[row][kk] = *(const float4*)&Wmat[(size_t)(g * NU + u0 + ul) * NU + kloc + kk * 4];
        }
        __syncthreads();
#pragma unroll
        for (int kk = 0; kk < 8; ++kk) {
            float a0[2][4];
#pragma unroll
            for (int bb = 0; bb < 2; ++bb) {
                const float* ap = &actv[(b_lo + bb * 128) * 37 + kk * 4];
                a0[bb][0] = ap[0]; a0[bb][1] = ap[1]; a0[bb][2] = ap[2]; a0[bb][3] = ap[3];
            }
#pragma unroll
            for (int uii = 0; uii < 2; ++uii)
#pragma unroll
                for (int g = 0; g < 4; ++g) {
                    float4 w = wv[(up * 2 + uii) * 4 + g][kk];
#pragma unroll
                    for (int bb = 0; bb < 2; ++bb)
                        acc[bb][uii][g] += a0[bb][0] * w.x + a0[bb][1] * w.y
                                         + a0[bb][2] * w.z + a0[bb][3] * w.w;
                }
        }
    }

#pragma unroll
    for (int bb = 0; bb < 2; ++bb) {
        int b = b_lo + bb * 128;
        int u = u0 + up * 2;
        float2 cold = *(const float2*)&cc[(size_t)b * NU + u];
        float2 cnew, hnew;
#pragma unroll
        for (int uii = 0; uii < 2; ++uii) {
            float i_ = sigm(acc[bb][uii][0]);
            float f_ = sigm(acc[bb][uii][1]);
            float g_ = tanh_fast(acc[bb][uii][2]);
            float o_ = sigm(acc[bb][uii][3]);
            float co = uii ? cold.y : cold.x;
            float c2 = f_ * co + i_ * g_;
            float h2 = o_ * tanh_fast(c2);
            if (uii == 0) { cnew.x = c2; hnew.x = h2; } else { cnew.y = c2; hnew.y = h2; }
        }
        *(float2*)&cc[(size_t)b * NU + u] = cnew;
        *(float2*)&hc_w[(size_t)b * NU + u] = hnew;
    }
}

// ---------------------------------------------------------------------------
// head: out(256,32000) = hc @ Wout^T + bout. Classic 64x64 tile, 4x4 micro.
// grid (500, 4), block 256.
// ---------------------------------------------------------------------------
__global__ __launch_bounds__(256)
void head_k(const float* __restrict__ A,    // (256,1024)
            const float* __restrict__ W,    // (32000,1024)
            const float* __restrict__ bias,
            float* __restrict__ out)        // (256,32000)
{
    const int nb = blockIdx.x;
    const int mb = blockIdx.y;
    const int tid = threadIdx.x;
    const int tx = tid & 15, ty = tid >> 4;

    __shared__ float As[16][68];
    __shared__ float Bs[16][68];

    float acc[4][4] = {{0.f}};

    for (int k0 = 0; k0 < 1024; k0 += 16) {
        __syncthreads();
        {
            int row = tid >> 2, kk = tid & 3;
            float4 v = *(const float4*)&A[(size_t)(mb * 64 + row) * 1024 + k0 + kk * 4];
            As[kk * 4 + 0][row] = v.x; As[kk * 4 + 1][row] = v.y;
            As[kk * 4 + 2][row] = v.z; As[kk * 4 + 3][row] = v.w;
            float4 w = *(const float4*)&W[(size_t)(nb * 64 + row) * 1024 + k0 + kk * 4];
            Bs[kk * 4 + 0][row] = w.x; Bs[kk * 4 + 1][row] = w.y;
            Bs[kk * 4 + 2][row] = w.z; Bs[kk * 4 + 3][row] = w.w;
        }
        __syncthreads();
#pragma unroll
        for (int k = 0; k < 16; ++k) {
            float4 av = *(const float4*)&As[k][tx * 4];
            float4 bv = *(const float4*)&Bs[k][ty * 4];
            float a[4] = {av.x, av.y, av.z, av.w};
            float b[4] = {bv.x, bv.y, bv.z, bv.w};
#pragma unroll
            for (int i = 0; i < 4; ++i)
#pragma unroll
                for (int j = 0; j < 4; ++j)
                    acc[i][j] += a[i] * b[j];
        }
    }

    float4 bv = *(const float4*)&bias[nb * 64 + ty * 4];
    float bb[4] = {bv.x, bv.y, bv.z, bv.w};
#pragma unroll
    for (int i = 0; i < 4; ++i) {
        float4 o;
        o.x = acc[i][0] + bb[0];
        o.y = acc[i][1] + bb[1];
        o.z = acc[i][2] + bb[2];
        o.w = acc[i][3] + bb[3];
        *(float4*)&out[(size_t)(mb * 64 + tx * 4 + i) * VV + nb * 64 + ty * 4] = o;
    }
}

extern "C" void kernel_launch(void* const* d_in, const int* in_sizes, int n_in,
                              void* d_out, int out_size, void* d_ws, size_t ws_size,
                              hipStream_t stream) {
    const int*   x     = (const int*)d_in[0];
    const float* W_emb = (const float*)d_in[1];
    const float* Wih_f = (const float*)d_in[2];
    const float* Whh_f = (const float*)d_in[3];
    const float* bih_f = (const float*)d_in[4];
    const float* bhh_f = (const float*)d_in[5];
    const float* Wih_b = (const float*)d_in[6];
    const float* Whh_b = (const float*)d_in[7];
    const float* bih_b = (const float*)d_in[8];
    const float* bhh_b = (const float*)d_in[9];
    const float* Wih_c = (const float*)d_in[10];
    const float* Whh_c = (const float*)d_in[11];
    const float* bih_c = (const float*)d_in[12];
    const float* bhh_c = (const float*)d_in[13];
    const float* Wout  = (const float*)d_in[14];
    const float* bout  = (const float*)d_in[15];
    const float* h0f   = (const float*)d_in[16];
    const float* c0f   = (const float*)d_in[17];
    const float* h0b   = (const float*)d_in[18];
    const float* c0b   = (const float*)d_in[19];
    const float* h0c   = (const float*)d_in[20];
    const float* c0c   = (const float*)d_in[21];

    float* ws = (float*)d_ws;
    const size_t BH = (size_t)BB * HH;   // 131072
    float* hf[2] = { ws + 0 * BH, ws + 1 * BH };
    float* cf    = ws + 2 * BH;
    float* hb[2] = { ws + 3 * BH, ws + 4 * BH };
    float* cb    = ws + 5 * BH;
    float* hc[2] = { ws + 6 * BH, ws + 8 * BH };   // each 2*BH
    float* cc    = ws + 10 * BH;                   // 2*BH

    hipMemcpyAsync(hf[0], h0f, BH * sizeof(float), hipMemcpyDeviceToDevice, stream);
    hipMemcpyAsync(cf,    c0f, BH * sizeof(float), hipMemcpyDeviceToDevice, stream);
    hipMemcpyAsync(hb[0], h0b, BH * sizeof(float), hipMemcpyDeviceToDevice, stream);
    hipMemcpyAsync(cb,    c0b, BH * sizeof(float), hipMemcpyDeviceToDevice, stream);
    hipMemcpyAsync(hc[0], h0c, 2 * BH * sizeof(float), hipMemcpyDeviceToDevice, stream);
    hipMemcpyAsync(cc,    c0c, 2 * BH * sizeof(float), hipMemcpyDeviceToDevice, stream);

    for (int t = 0; t < SS; ++t) {
        int r = t & 1, w = 1 - r;        // h ping-pong; final h_c lands in buf 0
        fb_step_k<<<dim3(256), dim3(256), 0, stream>>>(x, W_emb,
            Wih_f, Whh_f, bih_f, bhh_f, Wih_b, Whh_b, bih_b, bhh_b,
            hf[r], hf[w], cf, hb[r], hb[w], cb, t);
        comb_step_k<<<dim3(256), dim3(256), 0, stream>>>(hf[w], hb[w],
            Wih_c, Whh_c, bih_c, bhh_c, hc[r], hc[w], cc);
    }
    head_k<<<dim3(500, 4), dim3(256), 0, stream>>>(hc[0], Wout, bout, (float*)d_out);
}

// Round 2
// 4535.053 us; speedup vs baseline: 6.5945x; 6.5945x over previous
//
#include <hip/hip_runtime.h>

#define BB 256
#define SS 64
#define HH 512
#define VV 32000

typedef unsigned short u16;
typedef __attribute__((ext_vector_type(8))) short bf16x8;   // 8 bf16 = 4 VGPRs
typedef __attribute__((ext_vector_type(4))) float f32x4;    // MFMA 16x16 C/D

__device__ __forceinline__ float sigm(float x) { return 1.0f / (1.0f + __expf(-x)); }
__device__ __forceinline__ float tanh_fast(float x) { return 1.0f - 2.0f / (__expf(2.0f * x) + 1.0f); }
__device__ __forceinline__ u16 f2bf(float f) {              // RNE fp32 -> bf16
    unsigned u = __float_as_uint(f);
    return (u16)((u + 0x7fffu + ((u >> 16) & 1u)) >> 16);
}

// ---------------------------------------------------------------------------
// Pre-pass: pack [Wih | Whh] along K into bf16 matrices + bias sums.
//   Wf/Wb: (2048, 1024)  k<512 from Wih_{f,b}, else Whh_{f,b}
//   Wc:    (4096, 2048)  k<1024 from Wih_c, else Whh_c
// ---------------------------------------------------------------------------
__global__ __launch_bounds__(256)
void cvt_weights_k(const float* __restrict__ Wih_f, const float* __restrict__ Whh_f,
                   const float* __restrict__ bih_f, const float* __restrict__ bhh_f,
                   const float* __restrict__ Wih_b, const float* __restrict__ Whh_b,
                   const float* __restrict__ bih_b, const float* __restrict__ bhh_b,
                   const float* __restrict__ Wih_c, const float* __restrict__ Whh_c,
                   const float* __restrict__ bih_c, const float* __restrict__ bhh_c,
                   u16* __restrict__ Wf, u16* __restrict__ Wb, u16* __restrict__ Wc,
                   float* __restrict__ bsf, float* __restrict__ bsb, float* __restrict__ bsc)
{
    const int gid = blockIdx.x * 256 + threadIdx.x;
    if (gid < 2048)       bsf[gid] = bih_f[gid] + bhh_f[gid];
    else if (gid < 4096)  { int e = gid - 2048; bsb[e] = bih_b[e] + bhh_b[e]; }
    else if (gid < 8192)  { int e = gid - 4096; bsc[e] = bih_c[e] + bhh_c[e]; }

    const int NQ = 3145728;           // (2*2048*1024 + 4096*2048) / 4
    const int stride = gridDim.x * 256;
    for (int q = gid; q < NQ; q += stride) {
        const float* src; u16* dst;
        if (q < 524288) {
            int row = q >> 8, kq = (q & 255) << 2;
            src = (kq < 512) ? (Wih_f + row * 512 + kq) : (Whh_f + row * 512 + (kq - 512));
            dst = Wf + row * 1024 + kq;
        } else if (q < 1048576) {
            int q2 = q - 524288;
            int row = q2 >> 8, kq = (q2 & 255) << 2;
            src = (kq < 512) ? (Wih_b + row * 512 + kq) : (Whh_b + row * 512 + (kq - 512));
            dst = Wb + row * 1024 + kq;
        } else {
            int q2 = q - 1048576;
            int row = q2 >> 9, kq = (q2 & 511) << 2;
            src = (kq < 1024) ? (Wih_c + (size_t)row * 1024 + kq)
                              : (Whh_c + (size_t)row * 1024 + (kq - 1024));
            dst = Wc + (size_t)row * 2048 + kq;
        }
        float4 v = *(const float4*)src;
        *(ushort4*)dst = make_ushort4(f2bf(v.x), f2bf(v.y), f2bf(v.z), f2bf(v.w));
    }
}

// ---------------------------------------------------------------------------
// Pre-pass: initial states. h -> bf16, c -> fp32 copies (updated in place).
// ---------------------------------------------------------------------------
__global__ __launch_bounds__(256)
void init_state_k(const float* __restrict__ h0f, const float* __restrict__ c0f,
                  const float* __restrict__ h0b, const float* __restrict__ c0b,
                  const float* __restrict__ h0c, const float* __restrict__ c0c,
                  u16* __restrict__ hf0, u16* __restrict__ hb0, u16* __restrict__ hc0,
                  float* __restrict__ cf, float* __restrict__ cb, float* __restrict__ cc)
{
    const int gid = blockIdx.x * 256 + threadIdx.x;
    const int N1 = 131072;
    const int stride = gridDim.x * 256;
    for (int i = gid; i < 524288; i += stride) {
        if (i < N1)          hf0[i] = f2bf(h0f[i]);
        else if (i < 2 * N1) hb0[i - N1] = f2bf(h0b[i - N1]);
        else                 hc0[i - 2 * N1] = f2bf(h0c[i - 2 * N1]);
    }
    for (int i = gid; i < 524288; i += stride) {
        if (i < N1)          cf[i] = c0f[i];
        else if (i < 2 * N1) cb[i - N1] = c0b[i - N1];
        else                 cc[i - 2 * N1] = c0c[i - 2 * N1];
    }
}

// ---------------------------------------------------------------------------
// fb step: forward + backward cells, MFMA 16x16x32 bf16.
// 1024 waves = 256 blocks x 4 waves. wave -> (cell, m-tile 16, u-tile 16),
// owns all 4 gates (4 f32x4 accs). K = 512(emb inline-gather) + 512(h bf16).
// ---------------------------------------------------------------------------
__global__ __launch_bounds__(256)
void fb_step_mfma(const int* __restrict__ x, const float* __restrict__ W_emb,
                  const u16* __restrict__ Wf, const u16* __restrict__ Wb,
                  const float* __restrict__ bsf, const float* __restrict__ bsb,
                  const u16* __restrict__ hf_r, u16* __restrict__ hf_w, float* __restrict__ cf,
                  const u16* __restrict__ hb_r, u16* __restrict__ hb_w, float* __restrict__ cb,
                  int t)
{
    const int tid = threadIdx.x;
    const int lane = tid & 63;
    const int wv = blockIdx.x * 4 + (tid >> 6);
    const int cell = wv >> 9;
    const int rem = wv & 511;
    const int u0 = (rem & 31) << 4;
    const int m0 = (rem >> 5) << 4;
    const int l15 = lane & 15;
    const int quad = lane >> 4;

    const u16* Wp = cell ? Wb : Wf;
    const float* bs = cell ? bsb : bsf;
    const u16* h_r = cell ? hb_r : hf_r;
    u16* h_w = cell ? hb_w : hf_w;
    float* c = cell ? cb : cf;
    const int s2 = cell ? (SS - 1 - t) : t;

    // seq = emb.reshape(S,B,H): token(step, batch b) = x[s2*B + b]; padding_idx=0
    const int tok = x[s2 * BB + m0 + l15];
    const float zsel = (tok == 0) ? 0.0f : 1.0f;
    const float* aptr0 = W_emb + (size_t)tok * HH + quad * 8;
    const u16* aptr1 = h_r + (size_t)(m0 + l15) * HH + quad * 8;
    const u16* bp0 = Wp + ((size_t)(0 * HH + u0 + l15)) * 1024 + quad * 8;
    const u16* bp1 = Wp + ((size_t)(1 * HH + u0 + l15)) * 1024 + quad * 8;
    const u16* bp2 = Wp + ((size_t)(2 * HH + u0 + l15)) * 1024 + quad * 8;
    const u16* bp3 = Wp + ((size_t)(3 * HH + u0 + l15)) * 1024 + quad * 8;

    f32x4 acc0 = {0.f, 0.f, 0.f, 0.f}, acc1 = acc0, acc2 = acc0, acc3 = acc0;

    // phase 0: k in [0,512) — A from embedding (fp32 -> bf16 inline)
#pragma unroll 4
    for (int k = 0; k < 512; k += 32) {
        float4 v0 = *(const float4*)(aptr0 + k);
        float4 v1 = *(const float4*)(aptr0 + k + 4);
        bf16x8 a;
        a[0] = (short)f2bf(v0.x * zsel); a[1] = (short)f2bf(v0.y * zsel);
        a[2] = (short)f2bf(v0.z * zsel); a[3] = (short)f2bf(v0.w * zsel);
        a[4] = (short)f2bf(v1.x * zsel); a[5] = (short)f2bf(v1.y * zsel);
        a[6] = (short)f2bf(v1.z * zsel); a[7] = (short)f2bf(v1.w * zsel);
        bf16x8 b0 = *(const bf16x8*)(bp0 + k);
        bf16x8 b1 = *(const bf16x8*)(bp1 + k);
        bf16x8 b2 = *(const bf16x8*)(bp2 + k);
        bf16x8 b3 = *(const bf16x8*)(bp3 + k);
        acc0 = __builtin_amdgcn_mfma_f32_16x16x32_bf16(a, b0, acc0, 0, 0, 0);
        acc1 = __builtin_amdgcn_mfma_f32_16x16x32_bf16(a, b1, acc1, 0, 0, 0);
        acc2 = __builtin_amdgcn_mfma_f32_16x16x32_bf16(a, b2, acc2, 0, 0, 0);
        acc3 = __builtin_amdgcn_mfma_f32_16x16x32_bf16(a, b3, acc3, 0, 0, 0);
    }
    // phase 1: k in [512,1024) — A from h (bf16 direct)
#pragma unroll 4
    for (int k = 0; k < 512; k += 32) {
        bf16x8 a = *(const bf16x8*)(aptr1 + k);
        bf16x8 b0 = *(const bf16x8*)(bp0 + 512 + k);
        bf16x8 b1 = *(const bf16x8*)(bp1 + 512 + k);
        bf16x8 b2 = *(const bf16x8*)(bp2 + 512 + k);
        bf16x8 b3 = *(const bf16x8*)(bp3 + 512 + k);
        acc0 = __builtin_amdgcn_mfma_f32_16x16x32_bf16(a, b0, acc0, 0, 0, 0);
        acc1 = __builtin_amdgcn_mfma_f32_16x16x32_bf16(a, b1, acc1, 0, 0, 0);
        acc2 = __builtin_amdgcn_mfma_f32_16x16x32_bf16(a, b2, acc2, 0, 0, 0);
        acc3 = __builtin_amdgcn_mfma_f32_16x16x32_bf16(a, b3, acc3, 0, 0, 0);
    }

    // epilogue: D row = quad*4+reg (batch), col = l15 (unit). gates i,f,g,o
    const int u = u0 + l15;
    const float bi_ = bs[0 * HH + u], bf_ = bs[1 * HH + u];
    const float bg_ = bs[2 * HH + u], bo_ = bs[3 * HH + u];
#pragma unroll
    for (int r = 0; r < 4; ++r) {
        const int b = m0 + quad * 4 + r;
        const size_t idx = (size_t)b * HH + u;
        float i_ = sigm(acc0[r] + bi_);
        float f_ = sigm(acc1[r] + bf_);
        float g_ = tanh_fast(acc2[r] + bg_);
        float o_ = sigm(acc3[r] + bo_);
        float c2 = f_ * c[idx] + i_ * g_;
        c[idx] = c2;
        h_w[idx] = f2bf(o_ * tanh_fast(c2));
    }
}

// ---------------------------------------------------------------------------
// comb step: 2H=1024-unit cell. 1024 waves = 256 blocks x 4 waves.
// K = 512(hf) + 512(hb) + 1024(hc_prev), all bf16.
// ---------------------------------------------------------------------------
__global__ __launch_bounds__(256)
void comb_step_mfma(const u16* __restrict__ hfin, const u16* __restrict__ hbin,
                    const u16* __restrict__ Wc, const float* __restrict__ bsc,
                    const u16* __restrict__ hc_r, u16* __restrict__ hc_w,
                    float* __restrict__ cc)
{
    constexpr int NU = 2 * HH;  // 1024
    const int tid = threadIdx.x;
    const int lane = tid & 63;
    const int wv = blockIdx.x * 4 + (tid >> 6);
    const int u0 = (wv & 63) << 4;
    const int m0 = (wv >> 6) << 4;
    const int l15 = lane & 15;
    const int quad = lane >> 4;

    const u16* af = hfin + (size_t)(m0 + l15) * HH + quad * 8;
    const u16* ab = hbin + (size_t)(m0 + l15) * HH + quad * 8;
    const u16* ac = hc_r + (size_t)(m0 + l15) * NU + quad * 8;
    const u16* bp0 = Wc + ((size_t)(0 * NU + u0 + l15)) * 2048 + quad * 8;
    const u16* bp1 = Wc + ((size_t)(1 * NU + u0 + l15)) * 2048 + quad * 8;
    const u16* bp2 = Wc + ((size_t)(2 * NU + u0 + l15)) * 2048 + quad * 8;
    const u16* bp3 = Wc + ((size_t)(3 * NU + u0 + l15)) * 2048 + quad * 8;

    f32x4 acc0 = {0.f, 0.f, 0.f, 0.f}, acc1 = acc0, acc2 = acc0, acc3 = acc0;

#pragma unroll 4
    for (int k = 0; k < 512; k += 32) {
        bf16x8 a = *(const bf16x8*)(af + k);
        bf16x8 b0 = *(const bf16x8*)(bp0 + k);
        bf16x8 b1 = *(const bf16x8*)(bp1 + k);
        bf16x8 b2 = *(const bf16x8*)(bp2 + k);
        bf16x8 b3 = *(const bf16x8*)(bp3 + k);
        acc0 = __builtin_amdgcn_mfma_f32_16x16x32_bf16(a, b0, acc0, 0, 0, 0);
        acc1 = __builtin_amdgcn_mfma_f32_16x16x32_bf16(a, b1, acc1, 0, 0, 0);
        acc2 = __builtin_amdgcn_mfma_f32_16x16x32_bf16(a, b2, acc2, 0, 0, 0);
        acc3 = __builtin_amdgcn_mfma_f32_16x16x32_bf16(a, b3, acc3, 0, 0, 0);
    }
#pragma unroll 4
    for (int k = 0; k < 512; k += 32) {
        bf16x8 a = *(const bf16x8*)(ab + k);
        bf16x8 b0 = *(const bf16x8*)(bp0 + 512 + k);
        bf16x8 b1 = *(const bf16x8*)(bp1 + 512 + k);
        bf16x8 b2 = *(const bf16x8*)(bp2 + 512 + k);
        bf16x8 b3 = *(const bf16x8*)(bp3 + 512 + k);
        acc0 = __builtin_amdgcn_mfma_f32_16x16x32_bf16(a, b0, acc0, 0, 0, 0);
        acc1 = __builtin_amdgcn_mfma_f32_16x16x32_bf16(a, b1, acc1, 0, 0, 0);
        acc2 = __builtin_amdgcn_mfma_f32_16x16x32_bf16(a, b2, acc2, 0, 0, 0);
        acc3 = __builtin_amdgcn_mfma_f32_16x16x32_bf16(a, b3, acc3, 0, 0, 0);
    }
#pragma unroll 4
    for (int k = 0; k < 1024; k += 32) {
        bf16x8 a = *(const bf16x8*)(ac + k);
        bf16x8 b0 = *(const bf16x8*)(bp0 + 1024 + k);
        bf16x8 b1 = *(const bf16x8*)(bp1 + 1024 + k);
        bf16x8 b2 = *(const bf16x8*)(bp2 + 1024 + k);
        bf16x8 b3 = *(const bf16x8*)(bp3 + 1024 + k);
        acc0 = __builtin_amdgcn_mfma_f32_16x16x32_bf16(a, b0, acc0, 0, 0, 0);
        acc1 = __builtin_amdgcn_mfma_f32_16x16x32_bf16(a, b1, acc1, 0, 0, 0);
        acc2 = __builtin_amdgcn_mfma_f32_16x16x32_bf16(a, b2, acc2, 0, 0, 0);
        acc3 = __builtin_amdgcn_mfma_f32_16x16x32_bf16(a, b3, acc3, 0, 0, 0);
    }

    const int u = u0 + l15;
    const float bi_ = bsc[0 * NU + u], bf_ = bsc[1 * NU + u];
    const float bg_ = bsc[2 * NU + u], bo_ = bsc[3 * NU + u];
#pragma unroll
    for (int r = 0; r < 4; ++r) {
        const int b = m0 + quad * 4 + r;
        const size_t idx = (size_t)b * NU + u;
        float i_ = sigm(acc0[r] + bi_);
        float f_ = sigm(acc1[r] + bf_);
        float g_ = tanh_fast(acc2[r] + bg_);
        float o_ = sigm(acc3[r] + bo_);
        float c2 = f_ * cc[idx] + i_ * g_;
        cc[idx] = c2;
        hc_w[idx] = f2bf(o_ * tanh_fast(c2));
    }
}

// ---------------------------------------------------------------------------
// head: out(256,32000) = hc_bf16 @ bf16(Wout_fp32)^T + bout.
// 2000 blocks x 4 waves; wave = (m16, n64) -> 4 MFMA n-tiles. Memory-bound
// on the single pass over Wout fp32 (131 MB).
// ---------------------------------------------------------------------------
__global__ __launch_bounds__(256)
void head_mfma(const u16* __restrict__ A,        // (256,1024) bf16
               const float* __restrict__ W,      // (32000,1024) fp32
               const float* __restrict__ bias,
               float* __restrict__ out)          // (256,32000) fp32
{
    const int tid = threadIdx.x;
    const int lane = tid & 63;
    const int bi = blockIdx.x;
    const int mt = bi / 125;
    const int nb = bi % 125;
    const int m0 = mt << 4;
    const int n0 = nb * 256 + (tid >> 6) * 64;
    const int l15 = lane & 15;
    const int quad = lane >> 4;

    const u16* aptr = A + (size_t)(m0 + l15) * 1024 + quad * 8;
    const float* wp0 = W + (size_t)(n0 + 0 * 16 + l15) * 1024 + quad * 8;
    const float* wp1 = W + (size_t)(n0 + 1 * 16 + l15) * 1024 + quad * 8;
    const float* wp2 = W + (size_t)(n0 + 2 * 16 + l15) * 1024 + quad * 8;
    const float* wp3 = W + (size_t)(n0 + 3 * 16 + l15) * 1024 + quad * 8;

    f32x4 acc0 = {0.f, 0.f, 0.f, 0.f}, acc1 = acc0, acc2 = acc0, acc3 = acc0;

#pragma unroll 2
    for (int k = 0; k < 1024; k += 32) {
        bf16x8 a = *(const bf16x8*)(aptr + k);
        const float* wps[4] = {wp0, wp1, wp2, wp3};
        bf16x8 bfr[4];
#pragma unroll
        for (int nt = 0; nt < 4; ++nt) {
            float4 v0 = *(const float4*)(wps[nt] + k);
            float4 v1 = *(const float4*)(wps[nt] + k + 4);
            bf16x8 b;
            b[0] = (short)f2bf(v0.x); b[1] = (short)f2bf(v0.y);
            b[2] = (short)f2bf(v0.z); b[3] = (short)f2bf(v0.w);
            b[4] = (short)f2bf(v1.x); b[5] = (short)f2bf(v1.y);
            b[6] = (short)f2bf(v1.z); b[7] = (short)f2bf(v1.w);
            bfr[nt] = b;
        }
        acc0 = __builtin_amdgcn_mfma_f32_16x16x32_bf16(a, bfr[0], acc0, 0, 0, 0);
        acc1 = __builtin_amdgcn_mfma_f32_16x16x32_bf16(a, bfr[1], acc1, 0, 0, 0);
        acc2 = __builtin_amdgcn_mfma_f32_16x16x32_bf16(a, bfr[2], acc2, 0, 0, 0);
        acc3 = __builtin_amdgcn_mfma_f32_16x16x32_bf16(a, bfr[3], acc3, 0, 0, 0);
    }

    f32x4 accs[4] = {acc0, acc1, acc2, acc3};
#pragma unroll
    for (int nt = 0; nt < 4; ++nt) {
        const int n = n0 + nt * 16 + l15;
        const float bv = bias[n];
#pragma unroll
        for (int r = 0; r < 4; ++r)
            out[(size_t)(m0 + quad * 4 + r) * VV + n] = accs[nt][r] + bv;
    }
}

extern "C" void kernel_launch(void* const* d_in, const int* in_sizes, int n_in,
                              void* d_out, int out_size, void* d_ws, size_t ws_size,
                              hipStream_t stream) {
    const int*   x     = (const int*)d_in[0];
    const float* W_emb = (const float*)d_in[1];
    const float* Wih_f = (const float*)d_in[2];
    const float* Whh_f = (const float*)d_in[3];
    const float* bih_f = (const float*)d_in[4];
    const float* bhh_f = (const float*)d_in[5];
    const float* Wih_b = (const float*)d_in[6];
    const float* Whh_b = (const float*)d_in[7];
    const float* bih_b = (const float*)d_in[8];
    const float* bhh_b = (const float*)d_in[9];
    const float* Wih_c = (const float*)d_in[10];
    const float* Whh_c = (const float*)d_in[11];
    const float* bih_c = (const float*)d_in[12];
    const float* bhh_c = (const float*)d_in[13];
    const float* Wout  = (const float*)d_in[14];
    const float* bout  = (const float*)d_in[15];
    const float* h0f   = (const float*)d_in[16];
    const float* c0f   = (const float*)d_in[17];
    const float* h0b   = (const float*)d_in[18];
    const float* c0b   = (const float*)d_in[19];
    const float* h0c   = (const float*)d_in[20];
    const float* c0c   = (const float*)d_in[21];

    // ws bump allocation (~28.1 MiB), all offsets 16B-aligned
    char* p = (char*)d_ws;
    u16* Wf = (u16*)p; p += (size_t)2048 * 1024 * 2;
    u16* Wb = (u16*)p; p += (size_t)2048 * 1024 * 2;
    u16* Wc = (u16*)p; p += (size_t)4096 * 2048 * 2;
    float* bsf = (float*)p; p += 2048 * 4;
    float* bsb = (float*)p; p += 2048 * 4;
    float* bsc = (float*)p; p += 4096 * 4;
    u16* hf[2]; hf[0] = (u16*)p; p += 131072 * 2; hf[1] = (u16*)p; p += 131072 * 2;
    u16* hb[2]; hb[0] = (u16*)p; p += 131072 * 2; hb[1] = (u16*)p; p += 131072 * 2;
    u16* hc[2]; hc[0] = (u16*)p; p += 262144 * 2; hc[1] = (u16*)p; p += 262144 * 2;
    float* cf = (float*)p; p += 131072 * 4;
    float* cb = (float*)p; p += 131072 * 4;
    float* cc = (float*)p; p += 262144 * 4;

    cvt_weights_k<<<dim3(4096), dim3(256), 0, stream>>>(
        Wih_f, Whh_f, bih_f, bhh_f, Wih_b, Whh_b, bih_b, bhh_b,
        Wih_c, Whh_c, bih_c, bhh_c, Wf, Wb, Wc, bsf, bsb, bsc);
    init_state_k<<<dim3(1024), dim3(256), 0, stream>>>(
        h0f, c0f, h0b, c0b, h0c, c0c, hf[0], hb[0], hc[0], cf, cb, cc);

    for (int t = 0; t < SS; ++t) {
        const int r = t & 1, w = 1 - r;     // final hc lands in hc[0]
        fb_step_mfma<<<dim3(256), dim3(256), 0, stream>>>(
            x, W_emb, Wf, Wb, bsf, bsb,
            hf[r], hf[w], cf, hb[r], hb[w], cb, t);
        comb_step_mfma<<<dim3(256), dim3(256), 0, stream>>>(
            hf[w], hb[w], Wc, bsc, hc[r], hc[w], cc);
    }
    head_mfma<<<dim3(2000), dim3(256), 0, stream>>>(hc[0], Wout, bout, (float*)d_out);
}

// Round 3
// 2837.035 us; speedup vs baseline: 10.5415x; 1.5985x over previous
//
#include <hip/hip_runtime.h>

#define BB 256
#define SS 64
#define HH 512
#define VV 32000

typedef unsigned short u16;
typedef __attribute__((ext_vector_type(8))) short bf16x8;   // 8 bf16 = 4 VGPRs
typedef __attribute__((ext_vector_type(4))) float f32x4;    // MFMA 16x16 C/D

__device__ __forceinline__ float sigm(float x) { return 1.0f / (1.0f + __expf(-x)); }
__device__ __forceinline__ float tanh_fast(float x) { return 1.0f - 2.0f / (__expf(2.0f * x) + 1.0f); }
__device__ __forceinline__ u16 f2bf(float f) {              // RNE fp32 -> bf16
    unsigned u = __float_as_uint(f);
    return (u16)((u + 0x7fffu + ((u >> 16) & 1u)) >> 16);
}

// ---------------------------------------------------------------------------
// pack_k: one-time swizzle into MFMA fragment layouts (wave-task based).
//  Xfrag  [s][mt][kc][lane][8]   : embedded seq, A-fragment order, 16 MB
//  Wfsw/Wbsw [tile][kc 0..31][g][lane][8] : fused [Wih|Whh] f/b cells, 4 MB ea
//  Wcsw   [tile][kc 0..63][g][lane][8]    : fused [Wih_c|Whh_c], 16 MB
// B-fragment element for lane (l15,quad), slot j = W[row = g*NU+u0+l15][kc*32+quad*8+j]
// ---------------------------------------------------------------------------
__global__ __launch_bounds__(256)
void pack_k(const int* __restrict__ x, const float* __restrict__ W_emb,
            const float* __restrict__ Wih_f, const float* __restrict__ Whh_f,
            const float* __restrict__ Wih_b, const float* __restrict__ Whh_b,
            const float* __restrict__ Wih_c, const float* __restrict__ Whh_c,
            u16* __restrict__ Xfrag, u16* __restrict__ Wfsw,
            u16* __restrict__ Wbsw, u16* __restrict__ Wcsw)
{
    const int lane = threadIdx.x & 63;
    const int l15 = lane & 15, quad = lane >> 4;
    const int gw0 = blockIdx.x * 4 + (threadIdx.x >> 6);
    const int nw = gridDim.x * 4;
    for (int task = gw0; task < 40960; task += nw) {
        const float* src; u16* dst; float scale = 1.f;
        if (task < 16384) {                         // Xfrag: (s, mt, kc)
            int s = task >> 8, rem = task & 255, mt = rem >> 4, kc = rem & 15;
            int b = mt * 16 + l15;
            int tok = x[s * 256 + b];               // seq row s*256+b (raw reshape)
            scale = (tok == 0) ? 0.f : 1.f;         // padding_idx=0
            src = W_emb + (size_t)tok * 512 + kc * 32 + quad * 8;
            dst = Xfrag + ((size_t)(s * 16 + mt) * 16 + kc) * 512 + (size_t)lane * 8;
        } else if (task < 24576) {                  // Wf / Wb: (which, tile, kc, g)
            int e = task - 16384;
            int which = e >> 12; e &= 4095;
            int tile = e >> 7, rem = e & 127, kc = rem >> 2, g = rem & 3;
            int row = g * 512 + tile * 16 + l15;
            int k0 = kc * 32 + quad * 8;
            const float* Wih = which ? Wih_b : Wih_f;
            const float* Whh = which ? Whh_b : Whh_f;
            src = (k0 < 512) ? (Wih + (size_t)row * 512 + k0)
                             : (Whh + (size_t)row * 512 + (k0 - 512));
            u16* W = which ? Wbsw : Wfsw;
            dst = W + ((size_t)(tile * 32 + kc) * 4 + g) * 512 + (size_t)lane * 8;
        } else {                                    // Wc: (tile, kc, g)
            int e = task - 24576;
            int tile = e >> 8, rem = e & 255, kc = rem >> 2, g = rem & 3;
            int row = g * 1024 + tile * 16 + l15;
            int k0 = kc * 32 + quad * 8;
            src = (k0 < 1024) ? (Wih_c + (size_t)row * 1024 + k0)
                              : (Whh_c + (size_t)row * 1024 + (k0 - 1024));
            dst = Wcsw + ((size_t)(tile * 64 + kc) * 4 + g) * 512 + (size_t)lane * 8;
        }
        float4 v0 = *(const float4*)src;
        float4 v1 = *(const float4*)(src + 4);
        bf16x8 o;
        o[0] = (short)f2bf(v0.x * scale); o[1] = (short)f2bf(v0.y * scale);
        o[2] = (short)f2bf(v0.z * scale); o[3] = (short)f2bf(v0.w * scale);
        o[4] = (short)f2bf(v1.x * scale); o[5] = (short)f2bf(v1.y * scale);
        o[6] = (short)f2bf(v1.z * scale); o[7] = (short)f2bf(v1.w * scale);
        *(bf16x8*)dst = o;
    }
}

// ---------------------------------------------------------------------------
// init_k: bias sums + initial states (h -> bf16, c -> fp32 working copies)
// ---------------------------------------------------------------------------
__global__ __launch_bounds__(256)
void init_k(const float* __restrict__ bih_f, const float* __restrict__ bhh_f,
            const float* __restrict__ bih_b, const float* __restrict__ bhh_b,
            const float* __restrict__ bih_c, const float* __restrict__ bhh_c,
            const float* __restrict__ h0f, const float* __restrict__ c0f,
            const float* __restrict__ h0b, const float* __restrict__ c0b,
            const float* __restrict__ h0c, const float* __restrict__ c0c,
            float* __restrict__ bsf, float* __restrict__ bsb, float* __restrict__ bsc,
            u16* __restrict__ hf0, u16* __restrict__ hb0, u16* __restrict__ hc0,
            float* __restrict__ cf, float* __restrict__ cb, float* __restrict__ cc)
{
    const int gid = blockIdx.x * 256 + threadIdx.x;
    if (gid < 2048)       bsf[gid] = bih_f[gid] + bhh_f[gid];
    else if (gid < 4096)  { int e = gid - 2048; bsb[e] = bih_b[e] + bhh_b[e]; }
    else if (gid < 8192)  { int e = gid - 4096; bsc[e] = bih_c[e] + bhh_c[e]; }
    const int N1 = 131072, stride = gridDim.x * 256;
    for (int i = gid; i < 524288; i += stride) {
        if (i < N1)          { hf0[i] = f2bf(h0f[i]); cf[i] = c0f[i]; }
        else if (i < 2 * N1) { int e = i - N1; hb0[e] = f2bf(h0b[e]); cb[e] = c0b[e]; }
        else                 { int e = i - 2 * N1; hc0[e] = f2bf(h0c[e]); cc[e] = c0c[e]; }
    }
}

#define MFMA(a, b, c) __builtin_amdgcn_mfma_f32_16x16x32_bf16(a, b, c, 0, 0, 0)

// ---------------------------------------------------------------------------
// step_k: software-pipelined fused step. Launch t = 0..64.
//   blocks [0,256):  fb cells, step s=t        (skipped at t=64)
//   blocks [256,512): combiner, step s=t-1     (skipped at t=0)
// comb(t-1) reads hf/hb written by fb(t-1) in the PREVIOUS launch; fb(t)
// writes the other ping-pong buffer. 2048 waves/launch = 8 waves/CU.
// All B loads are single coalesced 1KB fragment fetches from swizzled weights.
// ---------------------------------------------------------------------------
__global__ __launch_bounds__(256)
void step_k(const u16* __restrict__ Xfrag,
            const u16* __restrict__ Wfsw, const u16* __restrict__ Wbsw,
            const u16* __restrict__ Wcsw,
            const float* __restrict__ bsf, const float* __restrict__ bsb,
            const float* __restrict__ bsc,
            const u16* __restrict__ hf_r, u16* __restrict__ hf_w, float* __restrict__ cf,
            const u16* __restrict__ hb_r, u16* __restrict__ hb_w, float* __restrict__ cb,
            const u16* __restrict__ hc_r, u16* __restrict__ hc_w, float* __restrict__ cc,
            int t)
{
    const int tid = threadIdx.x;
    const int wid = tid >> 6, lane = tid & 63;
    const int l15 = lane & 15, quad = lane >> 4;
    const f32x4 z = {0.f, 0.f, 0.f, 0.f};

    if (blockIdx.x < 256) {
        if (t >= SS) return;
        const int wv = blockIdx.x * 4 + wid;     // 0..1023
        const int cell = wv >> 9;
        const int rem = wv & 511;
        const int ut = rem & 31, mt = rem >> 5;
        const u16* Wsw = cell ? Wbsw : Wfsw;
        const float* bs = cell ? bsb : bsf;
        const u16* h_r = cell ? hb_r : hf_r;
        u16* h_w = cell ? hb_w : hf_w;
        float* c = cell ? cb : cf;
        const int s2 = cell ? (SS - 1 - t) : t;

        const u16* xb = Xfrag + ((size_t)(s2 * 16 + mt) * 16) * 512 + (size_t)lane * 8;
        const u16* hp = h_r + (size_t)(mt * 16 + l15) * 512 + quad * 8;
        const u16* wb = Wsw + (size_t)ut * 65536 + lane * 8;

        f32x4 a0 = z, a1 = z, a2 = z, a3 = z;
#pragma unroll 4
        for (int kc = 0; kc < 16; ++kc) {        // K 0..511: embedded input
            bf16x8 a = *(const bf16x8*)(xb + kc * 512);
            bf16x8 b0 = *(const bf16x8*)(wb + kc * 2048);
            bf16x8 b1 = *(const bf16x8*)(wb + kc * 2048 + 512);
            bf16x8 b2 = *(const bf16x8*)(wb + kc * 2048 + 1024);
            bf16x8 b3 = *(const bf16x8*)(wb + kc * 2048 + 1536);
            a0 = MFMA(a, b0, a0); a1 = MFMA(a, b1, a1);
            a2 = MFMA(a, b2, a2); a3 = MFMA(a, b3, a3);
        }
#pragma unroll 4
        for (int kc = 16; kc < 32; ++kc) {       // K 512..1023: recurrent h
            bf16x8 a = *(const bf16x8*)(hp + (kc - 16) * 32);
            bf16x8 b0 = *(const bf16x8*)(wb + kc * 2048);
            bf16x8 b1 = *(const bf16x8*)(wb + kc * 2048 + 512);
            bf16x8 b2 = *(const bf16x8*)(wb + kc * 2048 + 1024);
            bf16x8 b3 = *(const bf16x8*)(wb + kc * 2048 + 1536);
            a0 = MFMA(a, b0, a0); a1 = MFMA(a, b1, a1);
            a2 = MFMA(a, b2, a2); a3 = MFMA(a, b3, a3);
        }
        const int u = ut * 16 + l15;
        const float bi_ = bs[u], bf_ = bs[512 + u], bg_ = bs[1024 + u], bo_ = bs[1536 + u];
#pragma unroll
        for (int r = 0; r < 4; ++r) {
            const int b = mt * 16 + quad * 4 + r;
            const size_t idx = (size_t)b * 512 + u;
            float i_ = sigm(a0[r] + bi_);
            float f_ = sigm(a1[r] + bf_);
            float g_ = tanh_fast(a2[r] + bg_);
            float o_ = sigm(a3[r] + bo_);
            float c2 = f_ * c[idx] + i_ * g_;
            c[idx] = c2;
            h_w[idx] = f2bf(o_ * tanh_fast(c2));
        }
    } else {
        if (t == 0) return;
        const int wv = (blockIdx.x - 256) * 4 + wid;   // 0..1023
        const int ut = wv & 63, mt = wv >> 6;
        const u16* wb = Wcsw + (size_t)ut * 131072 + lane * 8;
        const u16* hfp = hf_r + (size_t)(mt * 16 + l15) * 512 + quad * 8;
        const u16* hbp = hb_r + (size_t)(mt * 16 + l15) * 512 + quad * 8;
        const u16* hcp = hc_r + (size_t)(mt * 16 + l15) * 1024 + quad * 8;

        f32x4 a0 = z, a1 = z, a2 = z, a3 = z;
#pragma unroll 4
        for (int kc = 0; kc < 16; ++kc) {        // K 0..511: hf
            bf16x8 a = *(const bf16x8*)(hfp + kc * 32);
            bf16x8 b0 = *(const bf16x8*)(wb + kc * 2048);
            bf16x8 b1 = *(const bf16x8*)(wb + kc * 2048 + 512);
            bf16x8 b2 = *(const bf16x8*)(wb + kc * 2048 + 1024);
            bf16x8 b3 = *(const bf16x8*)(wb + kc * 2048 + 1536);
            a0 = MFMA(a, b0, a0); a1 = MFMA(a, b1, a1);
            a2 = MFMA(a, b2, a2); a3 = MFMA(a, b3, a3);
        }
#pragma unroll 4
        for (int kc = 16; kc < 32; ++kc) {       // K 512..1023: hb
            bf16x8 a = *(const bf16x8*)(hbp + (kc - 16) * 32);
            bf16x8 b0 = *(const bf16x8*)(wb + kc * 2048);
            bf16x8 b1 = *(const bf16x8*)(wb + kc * 2048 + 512);
            bf16x8 b2 = *(const bf16x8*)(wb + kc * 2048 + 1024);
            bf16x8 b3 = *(const bf16x8*)(wb + kc * 2048 + 1536);
            a0 = MFMA(a, b0, a0); a1 = MFMA(a, b1, a1);
            a2 = MFMA(a, b2, a2); a3 = MFMA(a, b3, a3);
        }
#pragma unroll 4
        for (int kc = 32; kc < 64; ++kc) {       // K 1024..2047: hc_prev
            bf16x8 a = *(const bf16x8*)(hcp + (kc - 32) * 32);
            bf16x8 b0 = *(const bf16x8*)(wb + kc * 2048);
            bf16x8 b1 = *(const bf16x8*)(wb + kc * 2048 + 512);
            bf16x8 b2 = *(const bf16x8*)(wb + kc * 2048 + 1024);
            bf16x8 b3 = *(const bf16x8*)(wb + kc * 2048 + 1536);
            a0 = MFMA(a, b0, a0); a1 = MFMA(a, b1, a1);
            a2 = MFMA(a, b2, a2); a3 = MFMA(a, b3, a3);
        }
        const int u = ut * 16 + l15;
        const float bi_ = bsc[u], bf_ = bsc[1024 + u], bg_ = bsc[2048 + u], bo_ = bsc[3072 + u];
#pragma unroll
        for (int r = 0; r < 4; ++r) {
            const int b = mt * 16 + quad * 4 + r;
            const size_t idx = (size_t)b * 1024 + u;
            float i_ = sigm(a0[r] + bi_);
            float f_ = sigm(a1[r] + bf_);
            float g_ = tanh_fast(a2[r] + bg_);
            float o_ = sigm(a3[r] + bo_);
            float c2 = f_ * cc[idx] + i_ * g_;
            cc[idx] = c2;
            hc_w[idx] = f2bf(o_ * tanh_fast(c2));
        }
    }
}

// ---------------------------------------------------------------------------
// head_v2: out(256,32000) = hc @ bf16(Wout)^T + bout, Wout fetched ONCE.
// grid 500 blocks (64 vocab cols each) x 4 waves (64 batch rows each).
// Wave: 4 m-tiles x 4 n-tiles = 16 f32x4 accumulators.
// ---------------------------------------------------------------------------
__global__ __launch_bounds__(256)
void head_v2(const u16* __restrict__ A,        // (256,1024) bf16 row-major
             const float* __restrict__ W,      // (32000,1024) fp32
             const float* __restrict__ bias,
             float* __restrict__ out)          // (256,32000) fp32
{
    const int tid = threadIdx.x, wid = tid >> 6, lane = tid & 63;
    const int l15 = lane & 15, quad = lane >> 4;
    const int n0 = blockIdx.x * 64;
    const int m0 = wid * 64;

    const u16* ap = A + (size_t)(m0 + l15) * 1024 + quad * 8;
    const float* wp = W + (size_t)(n0 + l15) * 1024 + quad * 8;

    f32x4 acc[4][4];
#pragma unroll
    for (int i = 0; i < 4; ++i)
#pragma unroll
        for (int j = 0; j < 4; ++j) acc[i][j] = {0.f, 0.f, 0.f, 0.f};

#pragma unroll 2
    for (int kc = 0; kc < 32; ++kc) {
        bf16x8 bfr[4];
#pragma unroll
        for (int nt = 0; nt < 4; ++nt) {
            const float* s = wp + (size_t)nt * 16384 + kc * 32;
            float4 v0 = *(const float4*)s;
            float4 v1 = *(const float4*)(s + 4);
            bf16x8 b;
            b[0] = (short)f2bf(v0.x); b[1] = (short)f2bf(v0.y);
            b[2] = (short)f2bf(v0.z); b[3] = (short)f2bf(v0.w);
            b[4] = (short)f2bf(v1.x); b[5] = (short)f2bf(v1.y);
            b[6] = (short)f2bf(v1.z); b[7] = (short)f2bf(v1.w);
            bfr[nt] = b;
        }
#pragma unroll
        for (int mt = 0; mt < 4; ++mt) {
            bf16x8 a = *(const bf16x8*)(ap + (size_t)mt * 16384 + kc * 32);
            acc[mt][0] = MFMA(a, bfr[0], acc[mt][0]);
            acc[mt][1] = MFMA(a, bfr[1], acc[mt][1]);
            acc[mt][2] = MFMA(a, bfr[2], acc[mt][2]);
            acc[mt][3] = MFMA(a, bfr[3], acc[mt][3]);
        }
    }

#pragma unroll
    for (int nt = 0; nt < 4; ++nt) {
        const int n = n0 + nt * 16 + l15;
        const float bv = bias[n];
#pragma unroll
        for (int mt = 0; mt < 4; ++mt)
#pragma unroll
            for (int r = 0; r < 4; ++r)
                out[(size_t)(m0 + mt * 16 + quad * 4 + r) * VV + n] = acc[mt][nt][r] + bv;
    }
}

extern "C" void kernel_launch(void* const* d_in, const int* in_sizes, int n_in,
                              void* d_out, int out_size, void* d_ws, size_t ws_size,
                              hipStream_t stream) {
    const int*   x     = (const int*)d_in[0];
    const float* W_emb = (const float*)d_in[1];
    const float* Wih_f = (const float*)d_in[2];
    const float* Whh_f = (const float*)d_in[3];
    const float* bih_f = (const float*)d_in[4];
    const float* bhh_f = (const float*)d_in[5];
    const float* Wih_b = (const float*)d_in[6];
    const float* Whh_b = (const float*)d_in[7];
    const float* bih_b = (const float*)d_in[8];
    const float* bhh_b = (const float*)d_in[9];
    const float* Wih_c = (const float*)d_in[10];
    const float* Whh_c = (const float*)d_in[11];
    const float* bih_c = (const float*)d_in[12];
    const float* bhh_c = (const float*)d_in[13];
    const float* Wout  = (const float*)d_in[14];
    const float* bout  = (const float*)d_in[15];
    const float* h0f   = (const float*)d_in[16];
    const float* c0f   = (const float*)d_in[17];
    const float* h0b   = (const float*)d_in[18];
    const float* c0b   = (const float*)d_in[19];
    const float* h0c   = (const float*)d_in[20];
    const float* c0c   = (const float*)d_in[21];

    // ws bump allocation (~44 MiB), everything 16B-aligned
    char* p = (char*)d_ws;
    u16* Wfsw = (u16*)p; p += (size_t)2048 * 1024 * 2;          // 4 MB
    u16* Wbsw = (u16*)p; p += (size_t)2048 * 1024 * 2;          // 4 MB
    u16* Wcsw = (u16*)p; p += (size_t)4096 * 2048 * 2;          // 16 MB
    u16* Xfrag = (u16*)p; p += (size_t)8388608 * 2;             // 16 MB
    float* bsf = (float*)p; p += 2048 * 4;
    float* bsb = (float*)p; p += 2048 * 4;
    float* bsc = (float*)p; p += 4096 * 4;
    u16* hf[2]; hf[0] = (u16*)p; p += 131072 * 2; hf[1] = (u16*)p; p += 131072 * 2;
    u16* hb[2]; hb[0] = (u16*)p; p += 131072 * 2; hb[1] = (u16*)p; p += 131072 * 2;
    u16* hc[2]; hc[0] = (u16*)p; p += 262144 * 2; hc[1] = (u16*)p; p += 262144 * 2;
    float* cf = (float*)p; p += 131072 * 4;
    float* cb = (float*)p; p += 131072 * 4;
    float* cc = (float*)p; p += 262144 * 4;

    pack_k<<<dim3(2560), dim3(256), 0, stream>>>(
        x, W_emb, Wih_f, Whh_f, Wih_b, Whh_b, Wih_c, Whh_c,
        Xfrag, Wfsw, Wbsw, Wcsw);
    init_k<<<dim3(1024), dim3(256), 0, stream>>>(
        bih_f, bhh_f, bih_b, bhh_b, bih_c, bhh_c,
        h0f, c0f, h0b, c0b, h0c, c0c,
        bsf, bsb, bsc, hf[0], hb[0], hc[0], cf, cb, cc);

    // fb(s): reads h[s&1], writes h[(s+1)&1].  comb(s): reads hf/hb[(s+1)&1],
    // hc[s&1]; writes hc[(s+1)&1]. Launch t runs fb(t) + comb(t-1).
    for (int t = 0; t <= SS; ++t) {
        step_k<<<dim3(512), dim3(256), 0, stream>>>(
            Xfrag, Wfsw, Wbsw, Wcsw, bsf, bsb, bsc,
            hf[t & 1], hf[(t + 1) & 1], cf,
            hb[t & 1], hb[(t + 1) & 1], cb,
            hc[(t + 1) & 1], hc[t & 1], cc, t);
    }
    // final comb(63) wrote hc[0]
    head_v2<<<dim3(500), dim3(256), 0, stream>>>(hc[0], Wout, bout, (float*)d_out);
}

// Round 4
// 1948.825 us; speedup vs baseline: 15.3460x; 1.4558x over previous
//
#include <hip/hip_runtime.h>

#define BB 256
#define SS 64
#define HH 512
#define VV 32000

typedef unsigned short u16;
typedef __attribute__((ext_vector_type(8))) short bf16x8;   // 8 bf16 = 4 VGPRs
typedef __attribute__((ext_vector_type(4))) float f32x4;    // MFMA 16x16 C/D

__device__ __forceinline__ float sigm(float x) { return 1.0f / (1.0f + __expf(-x)); }
__device__ __forceinline__ float tanh_fast(float x) { return 1.0f - 2.0f / (__expf(2.0f * x) + 1.0f); }
__device__ __forceinline__ u16 f2bf(float f) {              // RNE fp32 -> bf16
    unsigned u = __float_as_uint(f);
    return (u16)((u + 0x7fffu + ((u >> 16) & 1u)) >> 16);
}
__device__ __forceinline__ bf16x8 ld_cvt8(const float* s) { // 8 fp32 -> bf16x8
    float4 v0 = *(const float4*)s, v1 = *(const float4*)(s + 4);
    bf16x8 b;
    b[0] = (short)f2bf(v0.x); b[1] = (short)f2bf(v0.y);
    b[2] = (short)f2bf(v0.z); b[3] = (short)f2bf(v0.w);
    b[4] = (short)f2bf(v1.x); b[5] = (short)f2bf(v1.y);
    b[6] = (short)f2bf(v1.z); b[7] = (short)f2bf(v1.w);
    return b;
}

#define MFMA(a, b, c) __builtin_amdgcn_mfma_f32_16x16x32_bf16(a, b, c, 0, 0, 0)

// ---------------------------------------------------------------------------
// pack_k: one-time swizzle into MFMA fragment layouts (wave-task based).
//  Xfrag  [s][mt][kc][lane][8]            : embedded seq, A-frag order, 16 MB
//  Wfsw/Wbsw [ut][kc 0..31][g][lane][8]   : fused [Wih|Whh] f/b, 4 MB each
//  Wcsw   [ut][kc 0..63][g][lane][8]      : fused [Wih_c|Whh_c], 16 MB
// B-frag elem (lane=(l15,quad), j) = W[row = g*NU + ut*16 + l15][kc*32+quad*8+j]
// ---------------------------------------------------------------------------
__global__ __launch_bounds__(256)
void pack_k(const int* __restrict__ x, const float* __restrict__ W_emb,
            const float* __restrict__ Wih_f, const float* __restrict__ Whh_f,
            const float* __restrict__ Wih_b, const float* __restrict__ Whh_b,
            const float* __restrict__ Wih_c, const float* __restrict__ Whh_c,
            u16* __restrict__ Xfrag, u16* __restrict__ Wfsw,
            u16* __restrict__ Wbsw, u16* __restrict__ Wcsw)
{
    const int lane = threadIdx.x & 63;
    const int l15 = lane & 15, quad = lane >> 4;
    const int gw0 = blockIdx.x * 4 + (threadIdx.x >> 6);
    const int nw = gridDim.x * 4;
    for (int task = gw0; task < 40960; task += nw) {
        const float* src; u16* dst; float scale = 1.f;
        if (task < 16384) {                         // Xfrag: (s, mt, kc)
            int s = task >> 8, rem = task & 255, mt = rem >> 4, kc = rem & 15;
            int b = mt * 16 + l15;
            int tok = x[s * 256 + b];               // raw reshape: row = s*256+b
            scale = (tok == 0) ? 0.f : 1.f;         // padding_idx=0
            src = W_emb + (size_t)tok * 512 + kc * 32 + quad * 8;
            dst = Xfrag + ((size_t)(s * 16 + mt) * 16 + kc) * 512 + (size_t)lane * 8;
        } else if (task < 24576) {                  // Wf / Wb: (which, ut, kc, g)
            int e = task - 16384;
            int which = e >> 12; e &= 4095;
            int ut = e >> 7, rem = e & 127, kc = rem >> 2, g = rem & 3;
            int row = g * 512 + ut * 16 + l15;
            int k0 = kc * 32 + quad * 8;
            const float* Wih = which ? Wih_b : Wih_f;
            const float* Whh = which ? Whh_b : Whh_f;
            src = (k0 < 512) ? (Wih + (size_t)row * 512 + k0)
                             : (Whh + (size_t)row * 512 + (k0 - 512));
            u16* W = which ? Wbsw : Wfsw;
            dst = W + ((size_t)(ut * 32 + kc) * 4 + g) * 512 + (size_t)lane * 8;
        } else {                                    // Wc: (ut, kc, g)
            int e = task - 24576;
            int ut = e >> 8, rem = e & 255, kc = rem >> 2, g = rem & 3;
            int row = g * 1024 + ut * 16 + l15;
            int k0 = kc * 32 + quad * 8;
            src = (k0 < 1024) ? (Wih_c + (size_t)row * 1024 + k0)
                              : (Whh_c + (size_t)row * 1024 + (k0 - 1024));
            dst = Wcsw + ((size_t)(ut * 64 + kc) * 4 + g) * 512 + (size_t)lane * 8;
        }
        float4 v0 = *(const float4*)src;
        float4 v1 = *(const float4*)(src + 4);
        bf16x8 o;
        o[0] = (short)f2bf(v0.x * scale); o[1] = (short)f2bf(v0.y * scale);
        o[2] = (short)f2bf(v0.z * scale); o[3] = (short)f2bf(v0.w * scale);
        o[4] = (short)f2bf(v1.x * scale); o[5] = (short)f2bf(v1.y * scale);
        o[6] = (short)f2bf(v1.z * scale); o[7] = (short)f2bf(v1.w * scale);
        *(bf16x8*)dst = o;
    }
}

// ---------------------------------------------------------------------------
// init_k: bias sums + initial states. h0 -> bf16 A-FRAGMENT layout, c -> fp32.
// frag addr for h[b][k], NKC frags/mt: ((b>>4)*NKC + (k>>5))*512 +
//   ((b&15) + ((k>>3)&3)*16)*8 + (k&7)
// ---------------------------------------------------------------------------
__global__ __launch_bounds__(256)
void init_k(const float* __restrict__ bih_f, const float* __restrict__ bhh_f,
            const float* __restrict__ bih_b, const float* __restrict__ bhh_b,
            const float* __restrict__ bih_c, const float* __restrict__ bhh_c,
            const float* __restrict__ h0f, const float* __restrict__ c0f,
            const float* __restrict__ h0b, const float* __restrict__ c0b,
            const float* __restrict__ h0c, const float* __restrict__ c0c,
            float* __restrict__ bsf, float* __restrict__ bsb, float* __restrict__ bsc,
            u16* __restrict__ hf0, u16* __restrict__ hb0, u16* __restrict__ hc0,
            float* __restrict__ cf, float* __restrict__ cb, float* __restrict__ cc)
{
    const int gid = blockIdx.x * 256 + threadIdx.x;
    if (gid < 2048)       bsf[gid] = bih_f[gid] + bhh_f[gid];
    else if (gid < 4096)  { int e = gid - 2048; bsb[e] = bih_b[e] + bhh_b[e]; }
    else if (gid < 8192)  { int e = gid - 4096; bsc[e] = bih_c[e] + bhh_c[e]; }
    const int stride = gridDim.x * 256;
    for (int i = gid; i < 131072; i += stride) {
        int b = i >> 9, k = i & 511;
        int dst = ((b >> 4) * 16 + (k >> 5)) * 512 + (((b & 15) + (((k >> 3) & 3) << 4)) << 3) + (k & 7);
        hf0[dst] = f2bf(h0f[i]);
        hb0[dst] = f2bf(h0b[i]);
        cf[i] = c0f[i];
        cb[i] = c0b[i];
    }
    for (int i = gid; i < 262144; i += stride) {
        int b = i >> 10, k = i & 1023;
        int dst = ((b >> 4) * 32 + (k >> 5)) * 512 + (((b & 15) + (((k >> 3) & 3) << 4)) << 3) + (k & 7);
        hc0[dst] = f2bf(h0c[i]);
        cc[i] = c0c[i];
    }
}

// One double-buffered 2-kc GEMM period: stage next B (gate w) to LDS,
// 16 MFMA (2 mt x 4 g x 2 kc), single barrier.
#define PERIODS(A0, A1, PS, PE, NPT)                                        \
  for (int p = (PS); p < (PE); ++p) {                                       \
    const int cur = p & 1, nxt = cur ^ 1;                                   \
    const int kl = p - (PS);                                                \
    bf16x8 sa, sb;                                                          \
    const bool pre = (p + 1 < (NPT));                                       \
    if (pre) {                                                              \
      sa = *(const bf16x8*)(wstage + (size_t)(2 * p + 2) * 2048);           \
      sb = *(const bf16x8*)(wstage + (size_t)(2 * p + 3) * 2048);           \
    }                                                                       \
    bf16x8 a00 = *(const bf16x8*)((A0) + (size_t)(2 * kl) * 512);           \
    bf16x8 a01 = *(const bf16x8*)((A1) + (size_t)(2 * kl) * 512);           \
    bf16x8 a10 = *(const bf16x8*)((A0) + (size_t)(2 * kl + 1) * 512);       \
    bf16x8 a11 = *(const bf16x8*)((A1) + (size_t)(2 * kl + 1) * 512);       \
    _Pragma("unroll")                                                       \
    for (int g = 0; g < 4; ++g) {                                           \
      bf16x8 b0 = *(const bf16x8*)&Bsh[cur][0][g][(size_t)lane * 8];        \
      bf16x8 b1 = *(const bf16x8*)&Bsh[cur][1][g][(size_t)lane * 8];        \
      acc[0][g] = MFMA(a00, b0, acc[0][g]);                                 \
      acc[1][g] = MFMA(a01, b0, acc[1][g]);                                 \
      acc[0][g] = MFMA(a10, b1, acc[0][g]);                                 \
      acc[1][g] = MFMA(a11, b1, acc[1][g]);                                 \
    }                                                                       \
    if (pre) {                                                              \
      *(bf16x8*)&Bsh[nxt][0][w][(size_t)lane * 8] = sa;                     \
      *(bf16x8*)&Bsh[nxt][1][w][(size_t)lane * 8] = sb;                     \
    }                                                                       \
    __syncthreads();                                                        \
  }

// ---------------------------------------------------------------------------
// step_k v4: 256 blocks, XCD-swizzled (blockIdx%8 = XCD), 4 waves = 4 gates.
//  slot<16 : fb cell step t   (cell = xcd>>2, ut = (xcd&3)*8+slot>>1, mh)
//  slot>=16: combiner step t-1 (ut = xcd*8 + (slot-16)>>1, mh)
// Per-XCD weight working set: 1 MB (fb) + 2 MB (comb) -> L2-resident.
// Wave: 2 m-tiles x 4 gates, B through LDS (staged once per block).
// ---------------------------------------------------------------------------
__global__ __launch_bounds__(256)
void step_k(const u16* __restrict__ Xfrag,
            const u16* __restrict__ Wfsw, const u16* __restrict__ Wbsw,
            const u16* __restrict__ Wcsw,
            const float* __restrict__ bsf, const float* __restrict__ bsb,
            const float* __restrict__ bsc,
            const u16* __restrict__ hf_r, u16* __restrict__ hf_w, float* __restrict__ cf,
            const u16* __restrict__ hb_r, u16* __restrict__ hb_w, float* __restrict__ cb,
            const u16* __restrict__ hc_r, u16* __restrict__ hc_w, float* __restrict__ cc,
            int t)
{
    __shared__ __align__(16) u16 Bsh[2][2][4][512];   // 16 KB
    const int tid = threadIdx.x;
    const int w = tid >> 6, lane = tid & 63;
    const int l15 = lane & 15, quad = lane >> 4;
    const int xcd = blockIdx.x & 7, slot = blockIdx.x >> 3;
    const f32x4 z = {0.f, 0.f, 0.f, 0.f};

    if (slot < 16) {
        // ---------------- fb cells, step t ----------------
        if (t >= SS) return;
        const int mh = slot & 1, cell = xcd >> 2;
        const int ut = (xcd & 3) * 8 + (slot >> 1);
        const int mt0 = mh * 8 + w * 2;
        const u16* Wsw = cell ? Wbsw : Wfsw;
        const float* bs = cell ? bsb : bsf;
        const u16* h_r = cell ? hb_r : hf_r;
        u16* h_w = cell ? hb_w : hf_w;
        float* c = cell ? cb : cf;
        const int s2 = cell ? (SS - 1 - t) : t;

        const u16* wstage = Wsw + (size_t)ut * 65536 + (size_t)w * 512 + (size_t)lane * 8;
        const u16* xb0 = Xfrag + ((size_t)(s2 * 16 + mt0) * 16) * 512 + (size_t)lane * 8;
        const u16* xb1 = xb0 + 16 * 512;
        const u16* hp0 = h_r + ((size_t)(mt0 * 16)) * 512 + (size_t)lane * 8;
        const u16* hp1 = hp0 + 16 * 512;

        f32x4 acc[2][4];
#pragma unroll
        for (int mi = 0; mi < 2; ++mi)
#pragma unroll
            for (int g = 0; g < 4; ++g) acc[mi][g] = z;

        {   // prologue: stage kc 0,1
            bf16x8 s0 = *(const bf16x8*)(wstage);
            bf16x8 s1 = *(const bf16x8*)(wstage + 2048);
            *(bf16x8*)&Bsh[0][0][w][(size_t)lane * 8] = s0;
            *(bf16x8*)&Bsh[0][1][w][(size_t)lane * 8] = s1;
            __syncthreads();
        }
        PERIODS(xb0, xb1, 0, 8, 16)     // K 0..511: embedded input
        PERIODS(hp0, hp1, 8, 16, 16)    // K 512..1023: recurrent h

        const int u = ut * 16 + l15;
        const float bi_ = bs[u], bf_ = bs[512 + u], bg_ = bs[1024 + u], bo_ = bs[1536 + u];
        const int fragk = ut >> 1;
        const int lanehi = ((ut & 1) * 2 + (l15 >> 3)) << 4;
        const int j = l15 & 7;
#pragma unroll
        for (int mi = 0; mi < 2; ++mi) {
            const int mt = mt0 + mi;
#pragma unroll
            for (int r = 0; r < 4; ++r) {
                const int b = mt * 16 + quad * 4 + r;
                const size_t ci = (size_t)b * 512 + u;
                float i_ = sigm(acc[mi][0][r] + bi_);
                float f_ = sigm(acc[mi][1][r] + bf_);
                float g_ = tanh_fast(acc[mi][2][r] + bg_);
                float o_ = sigm(acc[mi][3][r] + bo_);
                float c2 = f_ * c[ci] + i_ * g_;
                c[ci] = c2;
                h_w[(size_t)(mt * 16 + fragk) * 512 + (size_t)((quad * 4 + r) + lanehi) * 8 + j]
                    = f2bf(o_ * tanh_fast(c2));
            }
        }
    } else {
        // ---------------- combiner, step t-1 ----------------
        if (t == 0) return;
        const int cs = slot - 16;
        const int mh = cs & 1;
        const int ut = xcd * 8 + (cs >> 1);
        const int mt0 = mh * 8 + w * 2;

        const u16* wstage = Wcsw + (size_t)ut * 131072 + (size_t)w * 512 + (size_t)lane * 8;
        const u16* hfp0 = hf_r + ((size_t)(mt0 * 16)) * 512 + (size_t)lane * 8;
        const u16* hfp1 = hfp0 + 16 * 512;
        const u16* hbp0 = hb_r + ((size_t)(mt0 * 16)) * 512 + (size_t)lane * 8;
        const u16* hbp1 = hbp0 + 16 * 512;
        const u16* hcp0 = hc_r + ((size_t)(mt0 * 32)) * 512 + (size_t)lane * 8;
        const u16* hcp1 = hcp0 + 32 * 512;

        f32x4 acc[2][4];
#pragma unroll
        for (int mi = 0; mi < 2; ++mi)
#pragma unroll
            for (int g = 0; g < 4; ++g) acc[mi][g] = z;

        {
            bf16x8 s0 = *(const bf16x8*)(wstage);
            bf16x8 s1 = *(const bf16x8*)(wstage + 2048);
            *(bf16x8*)&Bsh[0][0][w][(size_t)lane * 8] = s0;
            *(bf16x8*)&Bsh[0][1][w][(size_t)lane * 8] = s1;
            __syncthreads();
        }
        PERIODS(hfp0, hfp1, 0, 8, 32)    // K 0..511: hf(t-1)
        PERIODS(hbp0, hbp1, 8, 16, 32)   // K 512..1023: hb(t-1)
        PERIODS(hcp0, hcp1, 16, 32, 32)  // K 1024..2047: hc(t-2)

        const int u = ut * 16 + l15;
        const float bi_ = bsc[u], bf_ = bsc[1024 + u], bg_ = bsc[2048 + u], bo_ = bsc[3072 + u];
        const int fragk = ut >> 1;
        const int lanehi = ((ut & 1) * 2 + (l15 >> 3)) << 4;
        const int j = l15 & 7;
#pragma unroll
        for (int mi = 0; mi < 2; ++mi) {
            const int mt = mt0 + mi;
#pragma unroll
            for (int r = 0; r < 4; ++r) {
                const int b = mt * 16 + quad * 4 + r;
                const size_t ci = (size_t)b * 1024 + u;
                float i_ = sigm(acc[mi][0][r] + bi_);
                float f_ = sigm(acc[mi][1][r] + bf_);
                float g_ = tanh_fast(acc[mi][2][r] + bg_);
                float o_ = sigm(acc[mi][3][r] + bo_);
                float c2 = f_ * cc[ci] + i_ * g_;
                cc[ci] = c2;
                hc_w[(size_t)(mt * 32 + fragk) * 512 + (size_t)((quad * 4 + r) + lanehi) * 8 + j]
                    = f2bf(o_ * tanh_fast(c2));
            }
        }
    }
}

// ---------------------------------------------------------------------------
// head_v3: out(256,32000) = hc(frag) @ bf16(Wout)^T + bout.
// 500 blocks x 4 waves. Wave w stages n-tile (bid*4+w) of Wout (fp32->bf16,
// once per block) into LDS; computes m-quarter (wid*4..+3 m-tiles) x 4 nt.
// W read once (131 MB, L3-warm); A from L2.
// ---------------------------------------------------------------------------
__global__ __launch_bounds__(256)
void head_v3(const u16* __restrict__ A,        // (256,1024) bf16 frag, NKC=32
             const float* __restrict__ W,      // (32000,1024) fp32
             const float* __restrict__ bias,
             float* __restrict__ out)          // (256,32000) fp32
{
    __shared__ __align__(16) u16 Bsh[2][2][4][512];   // 16 KB
    const int tid = threadIdx.x;
    const int w = tid >> 6, lane = tid & 63;
    const int l15 = lane & 15, quad = lane >> 4;
    const int bid = blockIdx.x;
    const int ntw = bid * 4 + w;                       // staged n-tile

    const float* wsrc = W + (size_t)(ntw * 16 + l15) * 1024 + (size_t)quad * 8;
    const u16* ha[4];
#pragma unroll
    for (int mi = 0; mi < 4; ++mi)
        ha[mi] = A + ((size_t)((w * 4 + mi) * 32)) * 512 + (size_t)lane * 8;

    f32x4 acc[4][4];
#pragma unroll
    for (int mi = 0; mi < 4; ++mi)
#pragma unroll
        for (int nt = 0; nt < 4; ++nt) acc[mi][nt] = {0.f, 0.f, 0.f, 0.f};

    {   // prologue: stage kc 0,1
        bf16x8 s0 = ld_cvt8(wsrc);
        bf16x8 s1 = ld_cvt8(wsrc + 32);
        *(bf16x8*)&Bsh[0][0][w][(size_t)lane * 8] = s0;
        *(bf16x8*)&Bsh[0][1][w][(size_t)lane * 8] = s1;
        __syncthreads();
    }
    for (int p = 0; p < 16; ++p) {
        const int cur = p & 1, nxt = cur ^ 1;
        bf16x8 sa, sb;
        const bool pre = (p + 1 < 16);
        if (pre) {
            sa = ld_cvt8(wsrc + (size_t)(2 * p + 2) * 32);
            sb = ld_cvt8(wsrc + (size_t)(2 * p + 3) * 32);
        }
        bf16x8 a0[4], a1[4];
#pragma unroll
        for (int mi = 0; mi < 4; ++mi) {
            a0[mi] = *(const bf16x8*)(ha[mi] + (size_t)(2 * p) * 512);
            a1[mi] = *(const bf16x8*)(ha[mi] + (size_t)(2 * p + 1) * 512);
        }
#pragma unroll
        for (int nt = 0; nt < 4; ++nt) {
            bf16x8 b0 = *(const bf16x8*)&Bsh[cur][0][nt][(size_t)lane * 8];
            bf16x8 b1 = *(const bf16x8*)&Bsh[cur][1][nt][(size_t)lane * 8];
#pragma unroll
            for (int mi = 0; mi < 4; ++mi) {
                acc[mi][nt] = MFMA(a0[mi], b0, acc[mi][nt]);
                acc[mi][nt] = MFMA(a1[mi], b1, acc[mi][nt]);
            }
        }
        if (pre) {
            *(bf16x8*)&Bsh[nxt][0][w][(size_t)lane * 8] = sa;
            *(bf16x8*)&Bsh[nxt][1][w][(size_t)lane * 8] = sb;
        }
        __syncthreads();
    }

#pragma unroll
    for (int nt = 0; nt < 4; ++nt) {
        const int n = (bid * 4 + nt) * 16 + l15;
        const float bv = bias[n];
#pragma unroll
        for (int mi = 0; mi < 4; ++mi) {
            const int mt = w * 4 + mi;
#pragma unroll
            for (int r = 0; r < 4; ++r)
                out[(size_t)(mt * 16 + quad * 4 + r) * VV + n] = acc[mi][nt][r] + bv;
        }
    }
}

extern "C" void kernel_launch(void* const* d_in, const int* in_sizes, int n_in,
                              void* d_out, int out_size, void* d_ws, size_t ws_size,
                              hipStream_t stream) {
    const int*   x     = (const int*)d_in[0];
    const float* W_emb = (const float*)d_in[1];
    const float* Wih_f = (const float*)d_in[2];
    const float* Whh_f = (const float*)d_in[3];
    const float* bih_f = (const float*)d_in[4];
    const float* bhh_f = (const float*)d_in[5];
    const float* Wih_b = (const float*)d_in[6];
    const float* Whh_b = (const float*)d_in[7];
    const float* bih_b = (const float*)d_in[8];
    const float* bhh_b = (const float*)d_in[9];
    const float* Wih_c = (const float*)d_in[10];
    const float* Whh_c = (const float*)d_in[11];
    const float* bih_c = (const float*)d_in[12];
    const float* bhh_c = (const float*)d_in[13];
    const float* Wout  = (const float*)d_in[14];
    const float* bout  = (const float*)d_in[15];
    const float* h0f   = (const float*)d_in[16];
    const float* c0f   = (const float*)d_in[17];
    const float* h0b   = (const float*)d_in[18];
    const float* c0b   = (const float*)d_in[19];
    const float* h0c   = (const float*)d_in[20];
    const float* c0c   = (const float*)d_in[21];

    // ws bump allocation (~44 MiB), all 16B-aligned
    char* p = (char*)d_ws;
    u16* Wfsw = (u16*)p; p += (size_t)2048 * 1024 * 2;          // 4 MB
    u16* Wbsw = (u16*)p; p += (size_t)2048 * 1024 * 2;          // 4 MB
    u16* Wcsw = (u16*)p; p += (size_t)4096 * 2048 * 2;          // 16 MB
    u16* Xfrag = (u16*)p; p += (size_t)8388608 * 2;             // 16 MB
    float* bsf = (float*)p; p += 2048 * 4;
    float* bsb = (float*)p; p += 2048 * 4;
    float* bsc = (float*)p; p += 4096 * 4;
    u16* hf[2]; hf[0] = (u16*)p; p += 131072 * 2; hf[1] = (u16*)p; p += 131072 * 2;
    u16* hb[2]; hb[0] = (u16*)p; p += 131072 * 2; hb[1] = (u16*)p; p += 131072 * 2;
    u16* hc[2]; hc[0] = (u16*)p; p += 262144 * 2; hc[1] = (u16*)p; p += 262144 * 2;
    float* cf = (float*)p; p += 131072 * 4;
    float* cb = (float*)p; p += 131072 * 4;
    float* cc = (float*)p; p += 262144 * 4;

    pack_k<<<dim3(2560), dim3(256), 0, stream>>>(
        x, W_emb, Wih_f, Whh_f, Wih_b, Whh_b, Wih_c, Whh_c,
        Xfrag, Wfsw, Wbsw, Wcsw);
    init_k<<<dim3(1024), dim3(256), 0, stream>>>(
        bih_f, bhh_f, bih_b, bhh_b, bih_c, bhh_c,
        h0f, c0f, h0b, c0b, h0c, c0c,
        bsf, bsb, bsc, hf[0], hb[0], hc[0], cf, cb, cc);

    // fb(s): reads h[s&1], writes h[(s+1)&1].  comb(s): reads hf/hb[(s+1)&1],
    // hc[s&1]; writes hc[(s+1)&1]. Launch t runs fb(t) + comb(t-1).
    for (int t = 0; t <= SS; ++t) {
        step_k<<<dim3(256), dim3(256), 0, stream>>>(
            Xfrag, Wfsw, Wbsw, Wcsw, bsf, bsb, bsc,
            hf[t & 1], hf[(t + 1) & 1], cf,
            hb[t & 1], hb[(t + 1) & 1], cb,
            hc[(t + 1) & 1], hc[t & 1], cc, t);
    }
    // final comb(63) wrote hc[0]
    head_v3<<<dim3(500), dim3(256), 0, stream>>>(hc[0], Wout, bout, (float*)d_out);
}